// Round 10
// baseline (132.936 us; speedup 1.0000x reference)
//
#include <hip/hip_runtime.h>
#include <stdint.h>

// Problem constants
#define BB 2
#define SS 2048
#define DD 1024
#define HH 16
#define DK 64

// 0.125 (1/sqrt(DK)) * log2(e): QK^T scores land in log2 domain -> exp2 softmax
#define QSCALE 0.1803368801111204f
// finite mask sentinel
#define NEGS -1.0e30f

typedef short s16x8 __attribute__((ext_vector_type(8)));
typedef float f32x4 __attribute__((ext_vector_type(4)));
typedef unsigned short u16x4 __attribute__((ext_vector_type(4)));
typedef unsigned int u32x4 __attribute__((ext_vector_type(4)));

static __device__ __forceinline__ unsigned short f2bf(float f) {
  unsigned int u = __builtin_bit_cast(unsigned int, f);
  u = (u + 0x7fffu + ((u >> 16) & 1u)) >> 16;
  return (unsigned short)u;
}

static __device__ __forceinline__ float bf2f(unsigned short s) {
  unsigned int u = ((unsigned int)s) << 16;
  return __builtin_bit_cast(float, u);
}

// v_cvt_pk_bf16_f32: lo -> low 16, hi -> high 16 (RTNE)
static __device__ __forceinline__ unsigned int cvtpk(float lo, float hi) {
  unsigned int r;
  asm("v_cvt_pk_bf16_f32 %0, %1, %2" : "=v"(r) : "v"(lo), "v"(hi));
  return r;
}

static __device__ __forceinline__ f32x4 mfma16(s16x8 a, s16x8 b, f32x4 c) {
  return __builtin_amdgcn_mfma_f32_16x16x32_bf16(a, b, c, 0, 0, 0);
}

static __device__ __forceinline__ void gload_lds16(const void* g, void* l) {
  __builtin_amdgcn_global_load_lds(
      (const __attribute__((address_space(1))) unsigned int*)g,
      (__attribute__((address_space(3))) unsigned int*)l, 16, 0, 0);
}

// ---------------- fp32 -> bf16 convert, all 3 tensors in one launch ----------------
__global__ __launch_bounds__(256) void cvt3_kernel(const float* __restrict__ q,
                                                   const float* __restrict__ k,
                                                   const float* __restrict__ v,
                                                   unsigned short* __restrict__ qb,
                                                   unsigned short* __restrict__ kb,
                                                   unsigned short* __restrict__ vb) {
  int sel = blockIdx.y;
  const float* in = (sel == 0) ? q : ((sel == 1) ? k : v);
  unsigned short* out = (sel == 0) ? qb : ((sel == 1) ? kb : vb);
  int i = blockIdx.x * 256 + threadIdx.x;
  f32x4 vv = ((const f32x4*)in)[i];
  u16x4 o;
  o.x = f2bf(vv.x); o.y = f2bf(vv.y); o.z = f2bf(vv.z); o.w = f2bf(vv.w);
  ((u16x4*)out)[i] = o;
}

// ---------------- all 4 W [K][N] fp32 -> WT [N][K] bf16 in one launch ----------------
__global__ __launch_bounds__(256) void transpose_w4_kernel(const float* __restrict__ Wq,
                                                           const float* __restrict__ Wk,
                                                           const float* __restrict__ Wv,
                                                           const float* __restrict__ Wo,
                                                           unsigned short* __restrict__ WTbase) {
  __shared__ float t[32][33];
  int z = blockIdx.z;
  const float* W = (z == 0) ? Wq : ((z == 1) ? Wk : ((z == 2) ? Wv : Wo));
  float scale = (z == 0) ? QSCALE : 1.0f;
  unsigned short* WT = WTbase + (size_t)z * DD * DD;
  int n0 = blockIdx.x * 32, k0 = blockIdx.y * 32;
  int tx = threadIdx.x, ty = threadIdx.y;
  for (int i = 0; i < 4; ++i)
    t[ty + 8 * i][tx] = W[(size_t)(k0 + ty + 8 * i) * DD + n0 + tx];
  __syncthreads();
  for (int i = 0; i < 4; ++i)
    WT[(size_t)(n0 + ty + 8 * i) * DD + k0 + tx] = f2bf(t[tx][ty + 8 * i] * scale);
}

// ---------------- V [bh][S][DK] bf16 -> VT [bh][DK][S] bf16 ----------------
__global__ __launch_bounds__(256) void transpose_v_kernel(const unsigned short* __restrict__ V,
                                                          unsigned short* __restrict__ VT) {
  __shared__ unsigned short t[32][33];
  int s0 = blockIdx.x * 32, d0 = blockIdx.y * 32, bh = blockIdx.z;
  int tx = threadIdx.x, ty = threadIdx.y;
  const unsigned short* Vb = V + (size_t)bh * SS * DK;
  unsigned short* Tb = VT + (size_t)bh * DK * SS;
  for (int i = 0; i < 4; ++i)
    t[ty + 8 * i][tx] = Vb[(size_t)(s0 + ty + 8 * i) * DK + d0 + tx];
  __syncthreads();
  for (int i = 0; i < 4; ++i)
    Tb[(size_t)(d0 + ty + 8 * i) * SS + s0 + tx] = t[tx][ty + 8 * i];
}

// ---------------- fused QKV projection GEMM ----------------
__global__ __launch_bounds__(256) void gemm_qkv_kernel(
    const unsigned short* __restrict__ qb, const unsigned short* __restrict__ kb,
    const unsigned short* __restrict__ vb, const unsigned short* __restrict__ WTbase,
    const float* __restrict__ bq, const float* __restrict__ bk,
    const float* __restrict__ bv, unsigned short* __restrict__ Qh,
    unsigned short* __restrict__ Kh, unsigned short* __restrict__ Vh) {
  const int K = DD;
  __shared__ __align__(16) unsigned short Alds[128 * 32];
  __shared__ __align__(16) unsigned short Blds[128 * 32];
  int tid = threadIdx.x;
  int lane = tid & 63, wave = tid >> 6;
  int g = lane >> 4, r16 = lane & 15;
  int seg = blockIdx.y >> 5;
  int m0 = (blockIdx.y & 31) * 128, n0 = blockIdx.x * 128;
  int wm = (wave >> 1) * 64, wn = (wave & 1) * 64;

  const unsigned short* A = (seg == 0) ? qb : ((seg == 1) ? kb : vb);
  const unsigned short* BT = WTbase + (size_t)seg * DD * DD;
  const float* bias = (seg == 0) ? bq : ((seg == 1) ? bk : bv);
  unsigned short* outh = (seg == 0) ? Qh : ((seg == 1) ? Kh : Vh);
  float bsc = (seg == 0) ? QSCALE : 1.0f;

  f32x4 acc[4][4] = {};

  int c0 = tid, c1 = tid + 256;
  int arow0 = c0 >> 2, arow1 = c1 >> 2;
  int as0 = (c0 & 3) ^ ((arow0 >> 1) & 3);
  int as1 = (c1 & 3) ^ ((arow1 >> 1) & 3);

  for (int k0 = 0; k0 < K; k0 += 32) {
    __syncthreads();
    gload_lds16((const char*)(A + (size_t)(m0 + arow0) * K + k0) + as0 * 16,
                (char*)Alds + wave * 1024);
    gload_lds16((const char*)(A + (size_t)(m0 + arow1) * K + k0) + as1 * 16,
                (char*)Alds + wave * 1024 + 4096);
    gload_lds16((const char*)(BT + (size_t)(n0 + arow0) * K + k0) + as0 * 16,
                (char*)Blds + wave * 1024);
    gload_lds16((const char*)(BT + (size_t)(n0 + arow1) * K + k0) + as1 * 16,
                (char*)Blds + wave * 1024 + 4096);
    __syncthreads();

    s16x8 af[4], bfr[4];
#pragma unroll
    for (int mt = 0; mt < 4; ++mt) {
      int row = wm + mt * 16 + r16;
      int ch = g ^ ((row >> 1) & 3);
      af[mt] = *(const s16x8*)((const char*)Alds + row * 64 + ch * 16);
    }
#pragma unroll
    for (int nt = 0; nt < 4; ++nt) {
      int row = wn + nt * 16 + r16;
      int ch = g ^ ((row >> 1) & 3);
      bfr[nt] = *(const s16x8*)((const char*)Blds + row * 64 + ch * 16);
    }
#pragma unroll
    for (int mt = 0; mt < 4; ++mt)
#pragma unroll
      for (int nt = 0; nt < 4; ++nt)
        acc[mt][nt] = mfma16(af[mt], bfr[nt], acc[mt][nt]);
  }

#pragma unroll
  for (int nt = 0; nt < 4; ++nt) {
    int col = n0 + wn + nt * 16 + r16;
    int h = col >> 6, dk = col & (DK - 1);
    float bvv = bias[col] * bsc;
#pragma unroll
    for (int mt = 0; mt < 4; ++mt) {
#pragma unroll
      for (int rr = 0; rr < 4; ++rr) {
        int rowg = m0 + wm + mt * 16 + g * 4 + rr;
        int bb = rowg >> 11, s = rowg & (SS - 1);
        float val = acc[mt][nt][rr] + bvv;
        outh[(((size_t)bb * HH + h) * SS + s) * DK + dk] = f2bf(val);
      }
    }
  }
}

// ---------------- output GEMM: C[4096][1024] = ctx @ WoT^T + bo (fp32), 128x64 tile ----------------
__global__ __launch_bounds__(256) void gemm_out_kernel(const unsigned short* __restrict__ A,
                                                       const unsigned short* __restrict__ BT,
                                                       const float* __restrict__ bias,
                                                       float* __restrict__ out) {
  const int K = DD;
  __shared__ __align__(16) unsigned short Alds[128 * 32];
  __shared__ __align__(16) unsigned short Blds[64 * 32];
  int tid = threadIdx.x;
  int lane = tid & 63, wave = tid >> 6;
  int g = lane >> 4, r16 = lane & 15;
  int m0 = blockIdx.y * 128, n0 = blockIdx.x * 64;
  int wm = (wave >> 1) * 64, wn = (wave & 1) * 32;

  f32x4 acc[4][2] = {};

  int c0 = tid, c1 = tid + 256;
  int arow0 = c0 >> 2, arow1 = c1 >> 2;
  int as0 = (c0 & 3) ^ ((arow0 >> 1) & 3);
  int as1 = (c1 & 3) ^ ((arow1 >> 1) & 3);

  for (int k0 = 0; k0 < K; k0 += 32) {
    __syncthreads();
    gload_lds16((const char*)(A + (size_t)(m0 + arow0) * K + k0) + as0 * 16,
                (char*)Alds + wave * 1024);
    gload_lds16((const char*)(A + (size_t)(m0 + arow1) * K + k0) + as1 * 16,
                (char*)Alds + wave * 1024 + 4096);
    gload_lds16((const char*)(BT + (size_t)(n0 + arow0) * K + k0) + as0 * 16,
                (char*)Blds + wave * 1024);
    __syncthreads();

    s16x8 af[4], bfr[2];
#pragma unroll
    for (int mt = 0; mt < 4; ++mt) {
      int row = wm + mt * 16 + r16;
      int ch = g ^ ((row >> 1) & 3);
      af[mt] = *(const s16x8*)((const char*)Alds + row * 64 + ch * 16);
    }
#pragma unroll
    for (int nt = 0; nt < 2; ++nt) {
      int row = wn + nt * 16 + r16;
      int ch = g ^ ((row >> 1) & 3);
      bfr[nt] = *(const s16x8*)((const char*)Blds + row * 64 + ch * 16);
    }
#pragma unroll
    for (int mt = 0; mt < 4; ++mt)
#pragma unroll
      for (int nt = 0; nt < 2; ++nt)
        acc[mt][nt] = mfma16(af[mt], bfr[nt], acc[mt][nt]);
  }

#pragma unroll
  for (int nt = 0; nt < 2; ++nt) {
    int col = n0 + wn + nt * 16 + r16;
    float bvv = bias[col];
#pragma unroll
    for (int mt = 0; mt < 4; ++mt) {
#pragma unroll
      for (int rr = 0; rr < 4; ++rr) {
        int rowg = m0 + wm + mt * 16 + g * 4 + rr;
        out[(size_t)rowg * DD + col] = acc[mt][nt][rr] + bvv;
      }
    }
  }
}

// ---------------- causal flash attention, split-pair (flash-decoding) ----------------
// Pair (pid, 31-pid) has 33 kv-tiles. Block half hf=0: all of segA (q-tile pid,
// pid+1 tiles, COMPLETE -> writes final ctx) + first 16-pid segB tiles (partial).
// Block half hf=1: last 16 segB tiles (partial). -> 1024 uniform blocks (17/16
// tiles), 4 blocks/CU. q-tile 31-pid merged from exactly 2 partials by
// combine_kernel. Partials: normalized O (bf16) + (m,l) f32, slot = bh*16+pid.
// Sync: __syncthreads() (fence + vmcnt/lgkm drain + barrier). Raw s_barrier
// is NOT a compiler memory fence — r9's raw-barrier variant let the compiler
// hoist LDS reads above the barrier => timing-dependent corruption.
__global__ __launch_bounds__(256) void attn_kernel(const unsigned short* __restrict__ Qh,
                                                   const unsigned short* __restrict__ Kh,
                                                   const unsigned short* __restrict__ VhT,
                                                   unsigned short* __restrict__ ctx,
                                                   unsigned short* __restrict__ Opart,
                                                   float2* __restrict__ mlpart) {
  __shared__ __align__(16) unsigned short Klds[2][64 * 64];  // [key][dk], swz (r&3)|(((r>>3)&1)<<2)
  __shared__ __align__(16) unsigned short Vlds[2][64 * 64];  // [d][key], swz r&7

  int tid = threadIdx.x;
  int lane = tid & 63, wave = tid >> 6;
  int g = lane >> 4, r16 = lane & 15;
  int bid = blockIdx.x;
  int x = bid >> 3;
  int pid = x & 15;
  int hf = (x >> 4) & 1;
  int bh = ((x >> 5) << 3) | (bid & 7);

  int tilesA = hf ? 0 : pid + 1;           // segA tile count (h0 only)
  int NT = hf ? 16 : 17;
  int q0A = pid * 64, q0B = (31 - pid) * 64;
  int kvoffB = hf ? (16 - pid) : 0;        // h1 segB starts at tile 16-pid

  const unsigned short* Qb = Qh + (size_t)bh * SS * DK;
  const char* Kb = (const char*)(Kh + (size_t)bh * SS * DK);
  const char* Vb = (const char*)(VhT + (size_t)bh * DK * SS);

  // K-frag read constants: row(nt) = 8a + b + 4*(nt&1) + 32*(nt>>1); swizzle sk = b + 4*(a&1)
  int a_ = r16 >> 2, b_ = r16 & 3;
  int rbase = 8 * a_ + b_;
  int sk = b_ + 4 * (a_ & 1);

  // staging geometry; pre-swizzled source
  int c0 = tid, c1 = tid + 256;
  int row0 = c0 >> 3, row1 = c1 >> 3;
  int skst0 = ((row0 & 3) | (((row0 >> 3) & 1) << 2));
  int skst1 = ((row1 & 3) | (((row1 >> 3) & 1) << 2));
  int kc0 = (c0 & 7) ^ skst0, kc1 = (c1 & 7) ^ skst1;
  int vc0 = (c0 & 7) ^ (row0 & 7), vc1 = (c1 & 7) ^ (row1 & 7);

  // tile t -> kv byte-tile index
#define KV_OF(t) ((hf ? (kvoffB + (t)) : (((t) < tilesA) ? (t) : ((t) - tilesA))) * 64)
#define STAGE_KV(buf, kv0)                                                   \
  do {                                                                       \
    gload_lds16(Kb + ((size_t)((kv0) + row0) * 128) + kc0 * 16,              \
                (char*)Klds[buf] + wave * 1024);                             \
    gload_lds16(Kb + ((size_t)((kv0) + row1) * 128) + kc1 * 16,              \
                (char*)Klds[buf] + wave * 1024 + 4096);                      \
    gload_lds16(Vb + ((size_t)row0 * SS + (kv0)) * 2 + vc0 * 16,             \
                (char*)Vlds[buf] + wave * 1024);                             \
    gload_lds16(Vb + ((size_t)row1 * SS + (kv0)) * 2 + vc1 * 16,             \
                (char*)Vlds[buf] + wave * 1024 + 4096);                      \
  } while (0)

  int b = bh >> 4, h = bh & (HH - 1);

  // starting segment: A for h0, B for h1
  int qw0 = (hf ? q0B : q0A) + wave * 16;
  s16x8 aq[2];
#pragma unroll
  for (int kc = 0; kc < 2; ++kc)
    aq[kc] = *(const s16x8*)(Qb + (size_t)(qw0 + r16) * DK + kc * 32 + g * 8);

  STAGE_KV(0, KV_OF(0));

  f32x4 accd[4] = {};  // [dsub]: O^T[d=dsub*16+4g+rr][q=qw0+r16]
  float mrow = -INFINITY, lrow = 0.0f;

  for (int t = 0; t < NT; ++t) {
    if (hf == 0 && t == tilesA) {
      // segA complete: write final output for q-tile pid, reset for segB partial
      float inv = 1.0f / lrow;
      int srow = qw0 + r16;
#pragma unroll
      for (int dsub = 0; dsub < 4; ++dsub) {
        int d0 = dsub * 16 + 4 * g;
        u16x4 o;
#pragma unroll
        for (int rr = 0; rr < 4; ++rr) o[rr] = f2bf(accd[dsub][rr] * inv);
        *(u16x4*)&ctx[(((size_t)b * SS + srow) * HH + h) * DK + d0] = o;
      }
      qw0 = q0B + wave * 16;
#pragma unroll
      for (int kc = 0; kc < 2; ++kc)
        aq[kc] = *(const s16x8*)(Qb + (size_t)(qw0 + r16) * DK + kc * 32 + g * 8);
#pragma unroll
      for (int dsub = 0; dsub < 4; ++dsub) accd[dsub] = (f32x4){0.f, 0.f, 0.f, 0.f};
      mrow = -INFINITY;
      lrow = 0.0f;
    }

    int kv0 = KV_OF(t);

    // full-fence barrier: drains staging (stage-1-ahead had a compute period
    // of latency cover) and orders LDS reads after all waves' stage loads.
    __syncthreads();
    if (t + 1 < NT) STAGE_KV((t + 1) & 1, KV_OF(t + 1));

    const char* Kc = (const char*)Klds[t & 1];
    const char* Vc = (const char*)Vlds[t & 1];

    // ---- QK^T (swapped): sf[nt][rr] = S[key = kv0+8g+4(nt&1)+rr+32(nt>>1)][q = qw0+r16]
    f32x4 sf[4] = {};
    __builtin_amdgcn_s_setprio(1);
#pragma unroll
    for (int kc = 0; kc < 2; ++kc) {
      s16x8 bk[4];
#pragma unroll
      for (int nt = 0; nt < 4; ++nt) {
        int row = rbase + 4 * (nt & 1) + 32 * (nt >> 1);
        int ch = (kc * 4 + g) ^ sk;
        bk[nt] = *(const s16x8*)(Kc + row * 128 + ch * 16);
      }
#pragma unroll
      for (int nt = 0; nt < 4; ++nt)
        sf[nt] = mfma16(bk[nt], aq[kc], sf[nt]);
    }
    __builtin_amdgcn_s_setprio(0);

    // ---- prefetch V fragments (hides LDS latency under softmax VALU)
    s16x8 av[2][4];
#pragma unroll
    for (int c = 0; c < 2; ++c)
#pragma unroll
      for (int dsub = 0; dsub < 4; ++dsub) {
        int row = dsub * 16 + r16;
        int ch = (c * 4 + g) ^ (row & 7);
        av[c][dsub] = *(const s16x8*)(Vc + row * 128 + ch * 16);
      }

    // ---- mask (diagonal tiles only; wave-uniform branch); finite sentinel
    if (kv0 + 63 > qw0) {
      int thr = qw0 + r16 - kv0 - 8 * g;  // key offset limit
#pragma unroll
      for (int nt = 0; nt < 4; ++nt) {
        int koff = 4 * (nt & 1) + 32 * (nt >> 1);
#pragma unroll
        for (int rr = 0; rr < 4; ++rr)
          if (koff + rr > thr) sf[nt][rr] = NEGS;
      }
    }

    // ---- online softmax (log2 domain)
    float tmax = NEGS;
#pragma unroll
    for (int nt = 0; nt < 4; ++nt)
#pragma unroll
      for (int rr = 0; rr < 4; ++rr) tmax = fmaxf(tmax, sf[nt][rr]);
    tmax = fmaxf(tmax, __shfl_xor(tmax, 16));
    tmax = fmaxf(tmax, __shfl_xor(tmax, 32));

    if (!__all(tmax <= mrow)) {  // exact defer: skip is numerically identical
      float mn = fmaxf(mrow, tmax);
      float fc = __builtin_amdgcn_exp2f(mrow - mn);
      lrow *= fc;
      mrow = mn;
#pragma unroll
      for (int dsub = 0; dsub < 4; ++dsub)
#pragma unroll
        for (int rr = 0; rr < 4; ++rr) accd[dsub][rr] *= fc;
    }

    float pf[4][4];
    float su = 0.0f;
#pragma unroll
    for (int nt = 0; nt < 4; ++nt)
#pragma unroll
      for (int rr = 0; rr < 4; ++rr) {
        float p = __builtin_amdgcn_exp2f(sf[nt][rr] - mrow);
        pf[nt][rr] = p;
        su += p;
      }
    su += __shfl_xor(su, 16);
    su += __shfl_xor(su, 32);
    lrow += su;

    // pack P^T fragments: chunk c holds keys c*32 + 8g..+7 in k-ascending order
    unsigned int pk[2][4];
#pragma unroll
    for (int c = 0; c < 2; ++c) {
      pk[c][0] = cvtpk(pf[2 * c][0], pf[2 * c][1]);
      pk[c][1] = cvtpk(pf[2 * c][2], pf[2 * c][3]);
      pk[c][2] = cvtpk(pf[2 * c + 1][0], pf[2 * c + 1][1]);
      pk[c][3] = cvtpk(pf[2 * c + 1][2], pf[2 * c + 1][3]);
    }

    // ---- PV (swapped): accd[dsub] += mfma(A=V^T rows, B=P^T)
    __builtin_amdgcn_s_setprio(1);
#pragma unroll
    for (int c = 0; c < 2; ++c) {
      s16x8 pb = __builtin_bit_cast(s16x8, *(u32x4*)pk[c]);
#pragma unroll
      for (int dsub = 0; dsub < 4; ++dsub)
        accd[dsub] = mfma16(av[c][dsub], pb, accd[dsub]);
    }
    __builtin_amdgcn_s_setprio(0);
  }

  // epilogue: write segB partial (slot = bh*16+pid, half hf)
  // normalized-O bf16 + (m,l) f32; both halves always non-empty.
  size_t prow = ((size_t)bh * 16 + pid) * 64 + wave * 16 + r16;
  float inv = 1.0f / lrow;
  unsigned short* Op = Opart + ((size_t)hf * 32768 + prow) * 64;
#pragma unroll
  for (int dsub = 0; dsub < 4; ++dsub) {
    int d0 = dsub * 16 + 4 * g;
    u16x4 o;
#pragma unroll
    for (int rr = 0; rr < 4; ++rr) o[rr] = f2bf(accd[dsub][rr] * inv);
    *(u16x4*)&Op[d0] = o;
  }
  if (g == 0) mlpart[(size_t)hf * 32768 + prow] = make_float2(mrow, lrow);
#undef STAGE_KV
#undef KV_OF
}

// ---------------- combine 2 partials per B q-row ----------------
__global__ __launch_bounds__(256) void combine_kernel(const unsigned short* __restrict__ Opart,
                                                      const float2* __restrict__ mlpart,
                                                      unsigned short* __restrict__ ctx) {
  int idx = blockIdx.x * 256 + threadIdx.x;
  int row = idx >> 4;          // 32768 rows
  int d0 = (idx & 15) * 4;
  float2 ml0 = mlpart[row];
  float2 ml1 = mlpart[32768 + row];
  float m = fmaxf(ml0.x, ml1.x);
  float w0 = __builtin_amdgcn_exp2f(ml0.x - m) * ml0.y;
  float w1 = __builtin_amdgcn_exp2f(ml1.x - m) * ml1.y;
  float inv = 1.0f / (w0 + w1);
  w0 *= inv;
  w1 *= inv;
  u16x4 a = *(const u16x4*)(Opart + (size_t)row * 64 + d0);
  u16x4 bb4 = *(const u16x4*)(Opart + ((size_t)32768 + row) * 64 + d0);
  u16x4 o;
#pragma unroll
  for (int j = 0; j < 4; ++j) o[j] = f2bf(bf2f(a[j]) * w0 + bf2f(bb4[j]) * w1);
  int p = row >> 6, rin = row & 63;
  int bh = p >> 4, pid = p & 15;
  int srow = (31 - pid) * 64 + rin;
  int b = bh >> 4, h = bh & (HH - 1);
  *(u16x4*)&ctx[(((size_t)b * SS + srow) * HH + h) * DK + d0] = o;
}

extern "C" void kernel_launch(void* const* d_in, const int* in_sizes, int n_in,
                              void* d_out, int out_size, void* d_ws, size_t ws_size,
                              hipStream_t stream) {
  const float* q = (const float*)d_in[0];
  const float* k = (const float*)d_in[1];
  const float* v = (const float*)d_in[2];
  // d_in[3] = mask: exact causal tril, implemented in-kernel
  const float* Wq = (const float*)d_in[4];
  const float* bq = (const float*)d_in[5];
  const float* Wk = (const float*)d_in[6];
  const float* bk = (const float*)d_in[7];
  const float* Wv = (const float*)d_in[8];
  const float* bv = (const float*)d_in[9];
  const float* Wo = (const float*)d_in[10];
  const float* bo = (const float*)d_in[11];

  // Workspace layout (56 MB):
  //   [ 0, 8)  qb  -> reused as ctx
  //   [ 8,16)  kb  -> reused as Opart (2 x 4MB, dead after gemm_qkv)
  //   [16,24)  vb  -> reused as VhT
  //   [24,32)  WT[4]; WqT region [24,26) -> reused as mlpart (512KB, dead after gemm_qkv)
  //   [32,40) Qh   [40,48) Kh   [48,56) Vh
  char* ws = (char*)d_ws;
  const size_t MB = 1ull << 20;
  unsigned short* qb = (unsigned short*)(ws + 0 * MB);
  unsigned short* kb = (unsigned short*)(ws + 8 * MB);
  unsigned short* vb = (unsigned short*)(ws + 16 * MB);
  unsigned short* WTbase = (unsigned short*)(ws + 24 * MB);
  unsigned short* WoT = (unsigned short*)(ws + 30 * MB);
  unsigned short* Qh = (unsigned short*)(ws + 32 * MB);
  unsigned short* Kh = (unsigned short*)(ws + 40 * MB);
  unsigned short* Vh = (unsigned short*)(ws + 48 * MB);
  unsigned short* VhT = (unsigned short*)(ws + 16 * MB);   // reuse vb
  unsigned short* ctx = (unsigned short*)(ws + 0 * MB);    // reuse qb
  unsigned short* Opart = (unsigned short*)(ws + 8 * MB);  // reuse kb (8MB)
  float2* mlpart = (float2*)(ws + 24 * MB);                // reuse WqT (512KB)

  const int n4 = BB * SS * DD / 4;

  cvt3_kernel<<<dim3(n4 / 256, 3), 256, 0, stream>>>(q, k, v, qb, kb, vb);

  dim3 tb(32, 8);
  transpose_w4_kernel<<<dim3(32, 32, 4), tb, 0, stream>>>(Wq, Wk, Wv, Wo, WTbase);

  gemm_qkv_kernel<<<dim3(8, 96), 256, 0, stream>>>(qb, kb, vb, WTbase,
                                                   bq, bk, bv, Qh, Kh, Vh);

  transpose_v_kernel<<<dim3(SS / 32, DK / 32, BB * HH), tb, 0, stream>>>(Vh, VhT);

  attn_kernel<<<1024, 256, 0, stream>>>(Qh, Kh, VhT, ctx, Opart, mlpart);

  combine_kernel<<<2048, 256, 0, stream>>>(Opart, mlpart, ctx);

  gemm_out_kernel<<<dim3(16, 32), 256, 0, stream>>>(ctx, WoT, bo, (float*)d_out);
}